// Round 25
// baseline (25.898 us; speedup 1.0000x reference)
//
#include <hip/hip_runtime.h>
#include <hip/hip_fp16.h>

#define OUTF 11008
#define INF  4096
#define NTILES 688

typedef unsigned int uint;
typedef unsigned long long ull;
typedef __attribute__((ext_vector_type(8))) _Float16 f16x8;  // MFMA A/B (4 VGPR)
typedef __attribute__((ext_vector_type(4))) float f32x4;     // MFMA C/D

typedef __attribute__((address_space(1))) void gvoid_t;
typedef __attribute__((address_space(3))) void svoid_t;

union UA { uint4 u4; uint u[4]; f16x8 v; };
union UH { uint u; __half2 h; };

#define WAITV(n) asm volatile("s_waitcnt vmcnt(" #n ")" ::: "memory")
#define WAITL()  asm volatile("s_waitcnt lgkmcnt(0)" ::: "memory")
#define SBAR()   __builtin_amdgcn_sched_barrier(0)
#define FENCE()  asm volatile("" ::: "memory")
#define BARRIER() { FENCE(); __builtin_amdgcn_s_barrier(); FENCE(); }

// R22 skeleton, minus LUT (VALU shift-table dequant), minus norms-in-LDS
// (norms in registers). LDS instruction count per iter per wave: 14 -> ~9.
__global__ __launch_bounds__(256, 4) void lin2bit_kernel(
    const float* __restrict__ x, const int* __restrict__ wq,
    const float* __restrict__ wn, const float* __restrict__ bias,
    float* __restrict__ out)
{
  // X0 8K | X1 8K | W0 4K | W1 4K = 24K -> 4+ blocks/CU
  __shared__ __align__(16) char lds[24576];
  char* X0 = lds;
  char* X1 = lds + 8192;
  char* W0 = lds + 16384;
  char* W1 = lds + 20480;

  const int tid = threadIdx.x;
  const int wv  = tid >> 6;
  const int l   = tid & 63;
  const int col = l & 15;            // A-row (m) / B-col (o)
  const int q   = l >> 4;            // lane covers k = 8q..8q+7 of each group
  const int o0  = (int)blockIdx.x << 4;

  const char* xb  = (const char*)x;
  const char* wqb = (const char*)wq;

  // X loads: wave's 4 m-rows, 1 KB each, coalesced; asm volatile (un-sinkable)
#define XLOAD(c, xr) { \
    _Pragma("unroll") \
    for (int rr = 0; rr < 4; ++rr) { \
      const int r = wv * 4 + rr; \
      const float* srcp = (const float*)(xb + (size_t)r * 16384 + (size_t)(c) * 1024) + l * 4; \
      asm volatile("global_load_dwordx4 %0, %1, off" \
                   : "=&v"((xr)[rr]) : "v"(srcp) : "memory"); \
    } }

  // X write: cvt f32->f16, swizzled ds_write_b64 (granule (l>>1)^(r&7), half l&1)
#define XWRITE(buf, xr) { \
    _Pragma("unroll") \
    for (int rr = 0; rr < 4; ++rr) { \
      const int r = wv * 4 + rr; \
      UH h0, h1; \
      h0.h = __floats2half2_rn((xr)[rr].x, (xr)[rr].y); \
      h1.h = __floats2half2_rn((xr)[rr].z, (xr)[rr].w); \
      *(uint2*)((buf) + r * 512 + (((l >> 1) ^ (r & 7)) << 4) + (l & 1) * 8) = \
          make_uint2(h0.u, h1.u); \
    } }

  // W chunk: 16 rows x 256B, 1 DMA/wave, 16B-granule source-side swizzle
#define WSTAGE(c, buf) { \
    const int r = wv * 4 + (l >> 4); \
    const char* src = wqb + (size_t)(o0 + r) * 4096 + (size_t)(c) * 256 \
                      + (((l & 15) ^ (r & 7)) << 4); \
    __builtin_amdgcn_global_load_lds((gvoid_t*)src, \
                                     (svoid_t*)((buf) + wv * 1024 + l * 16), 16, 0, 0); }

  // ---- norms to registers: chunk c needs norms[8c + 2wv + {0,1}] of row o0+col
  float2 nf2[16];
  {
    const float* np = wn + (size_t)(o0 + col) * 128 + 2 * wv;
#pragma unroll
    for (int c = 0; c < 16; ++c) {
      const float* p = np + 8 * c;
      asm volatile("global_load_dwordx2 %0, %1, off"
                   : "=&v"(nf2[c]) : "v"(p) : "memory");
    }
  }
  FENCE();

  float4 xrA[4], xrB[4];
  XLOAD(0, xrA);   FENCE();
  WSTAGE(0, W0);   FENCE();
  XLOAD(1, xrB);   FENCE();
  WSTAGE(1, W1);   FENCE();
  // FIFO: NF(16) XL0(4) W0(1) XL1(4) W1(1) = 26

  WAITV(5); SBAR();         // retire NF+XL0+W0; keep XL1(4)+W1(1)
  XWRITE(X0, xrA);
  WAITL(); BARRIER();       // X0 written block-wide; W0 retired all-waves

  f32x4 acc = {0.f, 0.f, 0.f, 0.f};
  const int c7 = col & 7;

  // VALU shift-table dequant (R4/R11-proven): 64-bit f16 table per group.
#define COMPUTE(c, xs, ws) { \
    const float2 nn = nf2[c]; \
    _Pragma("unroll") \
    for (int jj = 0; jj < 2; ++jj) { \
      const int g = wv * 2 + jj; \
      const float nv  = jj ? nn.y : nn.x; \
      const float nv3 = nv * 0.333f; \
      UH tlo, thi; \
      tlo.h = __floats2half2_rn(-nv, -nv3); \
      thi.h = __floats2half2_rn(nv3, nv); \
      const ull T = ((ull)thi.u << 32) | (ull)tlo.u; \
      const uint2 p = *(const uint2*)((ws) + col * 256 \
                        + (((g * 2 + (q >> 1)) ^ c7) << 4) + (q & 1) * 8); \
      UA A; A.u4 = *(const uint4*)((xs) + col * 512 + (((g * 4 + q) ^ c7) << 4)); \
      const uint p0 = p.x << 4, p1 = p.y << 4; \
      const uint w0 = (uint)(T >> (p0 & 0x30u)); \
      const uint w1 = (uint)(T >> ((p0 >> 2) & 0x30u)); \
      const uint w2 = (uint)(T >> ((p0 >> 4) & 0x30u)); \
      const uint w3 = (uint)(T >> ((p0 >> 6) & 0x30u)); \
      const uint w4 = (uint)(T >> (p1 & 0x30u)); \
      const uint w5 = (uint)(T >> ((p1 >> 2) & 0x30u)); \
      const uint w6 = (uint)(T >> ((p1 >> 4) & 0x30u)); \
      const uint w7 = (uint)(T >> ((p1 >> 6) & 0x30u)); \
      UA B; \
      B.u[0] = (w0 & 0xFFFFu) | (w1 << 16); \
      B.u[1] = (w2 & 0xFFFFu) | (w3 << 16); \
      B.u[2] = (w4 & 0xFFFFu) | (w5 << 16); \
      B.u[3] = (w6 & 0xFFFFu) | (w7 << 16); \
      acc = __builtin_amdgcn_mfma_f32_16x16x32_f16(A.v, B.v, acc, 0, 0, 0); \
    } }

  // iter c: compute c | load X(c+2) | barrier | W-stage c+2 | WAITV(5)
  // (retires XL(c+1)+W(c+1)) | write X(c+1) | barrier
#define ITER_FULL(c, XC, WC, XN, XRC, XRN) \
  COMPUTE(c, XC, WC) \
  XLOAD((c) + 2, XRC);  FENCE(); \
  BARRIER(); \
  WSTAGE((c) + 2, WC);  FENCE(); \
  WAITV(5); SBAR(); \
  XWRITE(XN, XRN); \
  WAITL(); BARRIER();

  ITER_FULL(0,  X0, W0, X1, xrA, xrB)
  ITER_FULL(1,  X1, W1, X0, xrB, xrA)
  ITER_FULL(2,  X0, W0, X1, xrA, xrB)
  ITER_FULL(3,  X1, W1, X0, xrB, xrA)
  ITER_FULL(4,  X0, W0, X1, xrA, xrB)
  ITER_FULL(5,  X1, W1, X0, xrB, xrA)
  ITER_FULL(6,  X0, W0, X1, xrA, xrB)
  ITER_FULL(7,  X1, W1, X0, xrB, xrA)
  ITER_FULL(8,  X0, W0, X1, xrA, xrB)
  ITER_FULL(9,  X1, W1, X0, xrB, xrA)
  ITER_FULL(10, X0, W0, X1, xrA, xrB)
  ITER_FULL(11, X1, W1, X0, xrB, xrA)
  ITER_FULL(12, X0, W0, X1, xrA, xrB)
  ITER_FULL(13, X1, W1, X0, xrB, xrA)
  // iter 14: X0/W0 hold chunk 14 (staged iter 12, retired iter 13)
  COMPUTE(14, X0, W0)
  BARRIER();
  WAITV(0); SBAR();
  XWRITE(X1, xrB);
  WAITL(); BARRIER();
  COMPUTE(15, X1, W1)
#undef ITER_FULL
#undef COMPUTE
#undef XLOAD
#undef XWRITE
#undef WSTAGE

  // ---- cross-wave K reduction (overlay on X0) + bias + store
  __syncthreads();
  float* red = (float*)lds;
  red[wv * 256 +   0 + l] = acc[0];
  red[wv * 256 +  64 + l] = acc[1];
  red[wv * 256 + 128 + l] = acc[2];
  red[wv * 256 + 192 + l] = acc[3];
  __syncthreads();
  const int t = tid;
  const float s = red[t] + red[256 + t] + red[512 + t] + red[768 + t];
  const int m  = ((t & 63) >> 4) * 4 + (t >> 6);   // D row = q*4 + reg
  const int oc = t & 15;                            // D col
  out[(size_t)m * OUTF + o0 + oc] = s + bias[o0 + oc];
}

extern "C" void kernel_launch(void* const* d_in, const int* in_sizes, int n_in,
                              void* d_out, int out_size, void* d_ws, size_t ws_size,
                              hipStream_t stream) {
  (void)in_sizes; (void)n_in; (void)out_size; (void)d_ws; (void)ws_size;
  const float* x    = (const float*)d_in[0];
  const int*   wq   = (const int*)d_in[1];
  const float* wn   = (const float*)d_in[2];
  const float* bias = (const float*)d_in[3];
  float*       out  = (float*)d_out;
  lin2bit_kernel<<<dim3(NTILES), dim3(256), 0, stream>>>(x, wq, wn, bias, out);
}